// Round 10
// baseline (60.450 us; speedup 1.0000x reference)
//
#include <hip/hip_runtime.h>
#include <stdint.h>

// Grouped linear: y[z] = coeff * x[z] @ W[idx[z]], idx sorted.
// C=8, U=V=512, Z=32768, fp32 in/out, bf16 MFMA compute.
//
// R10: x-stationary, barrier-free K-loop. Per block (64 rows x 256 cols):
// stage the 64 x-rows' FULL K=512 into LDS as bf16 (64 KB) once -> ONE
// barrier -> 4 autonomous waves (64x64 tile each) loop 16 K-steps with
// A-frag ds_reads from stationary LDS and B-frags loaded DIRECTLY to
// registers from pre-tiled L2-resident wsw (1KB-contiguous per frag,
// depth-2 ring prefetch). Zero sync in the K-loop; 2 blocks/CU so one
// block's compute covers the other's stage drain.

#define Cg 8
#define Ud 512
#define Vd 512
#define Zd 32768

#define KT 16                    // K-steps of 32
#define NBN 2                    // 2 col-blocks of 256
#define NBM_MAX 519              // sum ceil(cnt_g/64) <= 512+7
#define GRID_GEMM (NBM_MAX * NBN)    // 1038

#define WSW_US (Cg * 8 * KT * 4 * 512)   // [g][vb8][kt16][ct4][512us] = 4 MiB
#define WS_NEEDED ((size_t)WSW_US * 2 + 64)

typedef __attribute__((ext_vector_type(8))) short bf16x8;
typedef __attribute__((ext_vector_type(4))) float f32x4;
typedef __attribute__((ext_vector_type(4))) unsigned short us4;
typedef __attribute__((ext_vector_type(4))) float float4v;
typedef __attribute__((ext_vector_type(4))) unsigned int u32x4;

__device__ __forceinline__ unsigned short f2bf(float f) {
    unsigned int u = __float_as_uint(f);
    u += 0x7fffu + ((u >> 16) & 1u);   // round-to-nearest-even
    return (unsigned short)(u >> 16);
}
__device__ __forceinline__ unsigned int pk2(float lo, float hi) {
    return (unsigned int)f2bf(lo) | ((unsigned int)f2bf(hi) << 16);
}

// Subtile formula (16 rows x 32 k, us offset): (k>>3)*128 + (r&15)*8 + (k&7).
// Frag read (lane l): r=l15, k=l4*8.. -> byte l4*256+l15*16, 1KB contiguous
// per frag across the wave: conflict-free ds_read_b128 / coalesced global.

// ---------------- w converter (+ group starts) ----------------
// wsw: [g][vb(8 col-blocks of 64)][kt(16)][ct(4 col-subtiles of 16)][512 us]

__global__ __launch_bounds__(256)
void convert_w(const float* __restrict__ w, const int* __restrict__ idx,
               unsigned short* __restrict__ wsw, int* __restrict__ starts)
{
    const int t = blockIdx.x * 256 + threadIdx.x;    // 524288 tasks
    const int g   = t >> 16;
    const int rem = t & 65535;
    const int u0  = (rem >> 9) << 2;                 // 4 k-rows
    const int v   = rem & 511;
    const float* src = w + ((size_t)g << 18) + (size_t)u0 * Vd + v;
    us4 p;
    p[0] = f2bf(src[0]);
    p[1] = f2bf(src[Vd]);
    p[2] = f2bf(src[2 * Vd]);
    p[3] = f2bf(src[3 * Vd]);
    const int vb = v >> 6, ct = (v >> 4) & 3, c = v & 15;
    const int kt = u0 >> 5;
    const int off = ((((g * 8 + vb) * KT + kt) * 4 + ct) << 9)
                  + (((u0 & 31) >> 3) << 7) + (c << 3) + (u0 & 7);
    *(us4*)(wsw + off) = p;

    if (blockIdx.x == 0 && threadIdx.x < 9) {
        const int gq = threadIdx.x;
        int lo = 0;
        if (gq >= 8) lo = Zd;
        else {
            int hi = Zd;
            while (lo < hi) { int mid = (lo + hi) >> 1;
                              if (idx[mid] < gq) lo = mid + 1; else hi = mid; }
        }
        starts[gq] = lo;
    }
}

// ---------------- GEMM ----------------

__global__ __launch_bounds__(256, 2)
void sgl_gemm(const float* __restrict__ x,
              const unsigned short* __restrict__ wsw,
              const int* __restrict__ starts,
              const float* __restrict__ coeff,
              float* __restrict__ y)
{
    // A stationary: [kt(16)][rt(4)][512 us] = 64 KiB (64 rows x 512 k bf16)
    __shared__ unsigned short As[KT * 4 * 512];

    const int tid = threadIdx.x, lane = tid & 63, wave = tid >> 6;
    const int l15 = lane & 15, l4 = lane >> 4;

    // bijective XCD swizzle (m204): nwg=1038, q=129, r=6. Consecutive wk on
    // one XCD: bn-pairs of a row-panel + consecutive panels (same g) -> the
    // 512KB W[g] panel and x rows stay L2-resident per XCD.
    const int bid = blockIdx.x;
    const int xcd = bid & 7, io = bid >> 3;
    const int wk  = (xcd < 6) ? xcd * 130 + io : 780 + (xcd - 6) * 129 + io;
    const int bmp = wk >> 1, bn = wk & 1;

    // locate group for this padded 64-row block
    int s[9];
#pragma unroll
    for (int i = 0; i < 9; ++i) s[i] = starts[i];
    int g = -1, lblk = 0, ab = 0;
#pragma unroll
    for (int gg = 0; gg < 8; ++gg) {
        const int c  = s[gg + 1] - s[gg];
        const int nb = (c + 63) >> 6;
        if (g < 0 && bmp < ab + nb) { g = gg; lblk = bmp - ab; }
        ab += nb;
    }
    if (g < 0) return;
    const int start = s[g];
    const int cnt   = s[g + 1] - s[g];
    const int j0    = lblk << 6;

    // B: wave w covers global col-block vb = bn*4 + w (64 cols, full K)
    const unsigned short* wV = wsw
        + ((size_t)((g * 8 + bn * 4 + wave) * KT) << 11);   // *2048 us per kt
    const int bfr = (l4 << 7) + (l15 << 3);                 // frag lane offset

    // ---- stage: 64 rows x 512 k fp32 -> bf16 LDS, coalesced (4 thr/row) ----
    const int sr  = tid >> 2;                 // row 0..63
    const int sk0 = (tid & 3) << 7;           // k base 0,128,256,384
    const int rc  = (j0 + sr < cnt) ? (j0 + sr) : (cnt - 1);
    const float* sx = x + (size_t)(start + rc) * Ud + sk0;
    const int awb = ((sr >> 4) << 9) + ((sr & 15) << 3);   // row part of offset

#pragma unroll 4
    for (int j = 0; j < 16; ++j) {
        const int k0 = sk0 + j * 8;
        const float4v va = *(const float4v*)(sx + j * 8);
        const float4v vb2 = *(const float4v*)(sx + j * 8 + 4);
        u32x4 pw;
        pw[0] = pk2(va[0], va[1]);  pw[1] = pk2(va[2], va[3]);
        pw[2] = pk2(vb2[0], vb2[1]); pw[3] = pk2(vb2[2], vb2[3]);
        const int us = ((k0 >> 5) << 11) + awb + (((k0 & 31) >> 3) << 7);
        *(u32x4*)(&As[us]) = pw;
    }

    // B prefetch for kt=0,1 issued BEFORE the barrier (stay in flight; the
    // raw barrier below waits lgkm only, not vmcnt).
    bf16x8 bp0[4], bp1[4];
#pragma unroll
    for (int ni = 0; ni < 4; ++ni)
        bp0[ni] = *(const bf16x8*)(wV + (ni << 9) + bfr);
#pragma unroll
    for (int ni = 0; ni < 4; ++ni)
        bp1[ni] = *(const bf16x8*)(wV + 2048 + (ni << 9) + bfr);

    f32x4 acc[4][4];
#pragma unroll
    for (int mi = 0; mi < 4; ++mi)
#pragma unroll
        for (int ni = 0; ni < 4; ++ni)
            acc[mi][ni] = f32x4{0.f, 0.f, 0.f, 0.f};

    asm volatile("s_waitcnt lgkmcnt(0)" ::: "memory");   // ds_writes done
    __builtin_amdgcn_s_barrier();                        // ONLY barrier

    // ---- barrier-free K-loop: 16 steps, fully unrolled ----
#pragma unroll
    for (int kt = 0; kt < KT; ++kt) {
        bf16x8 a_[4], bu[4];
#pragma unroll
        for (int mi = 0; mi < 4; ++mi)
            a_[mi] = *(const bf16x8*)(&As[(kt << 11) + (mi << 9) + bfr]);
#pragma unroll
        for (int ni = 0; ni < 4; ++ni)
            bu[ni] = (kt & 1) ? bp1[ni] : bp0[ni];
        if (kt + 2 < KT) {                   // ring-2 prefetch: load kt+2
            if (kt & 1) {
#pragma unroll
                for (int ni = 0; ni < 4; ++ni)
                    bp1[ni] = *(const bf16x8*)(wV + ((kt + 2) << 11) + (ni << 9) + bfr);
            } else {
#pragma unroll
                for (int ni = 0; ni < 4; ++ni)
                    bp0[ni] = *(const bf16x8*)(wV + ((kt + 2) << 11) + (ni << 9) + bfr);
            }
        }
#pragma unroll
        for (int mi = 0; mi < 4; ++mi)
#pragma unroll
            for (int ni = 0; ni < 4; ++ni)
                acc[mi][ni] = __builtin_amdgcn_mfma_f32_16x16x32_bf16(
                    a_[mi], bu[ni], acc[mi][ni], 0, 0, 0);
    }

    // epilogue: C/D col=lane&15, row=(lane>>4)*4+q; mask padded rows
    const float cf = coeff[0];
    const bool full = (j0 + 64) <= cnt;
#pragma unroll
    for (int mi = 0; mi < 4; ++mi) {
        const int rb = mi * 16 + l4 * 4;
#pragma unroll
        for (int ni = 0; ni < 4; ++ni) {
            const int c = bn * 256 + wave * 64 + ni * 16 + l15;
#pragma unroll
            for (int q = 0; q < 4; ++q) {
                if (full || (j0 + rb + q) < cnt)
                    y[(size_t)(start + j0 + rb + q) * Vd + c] = acc[mi][ni][q] * cf;
            }
        }
    }
}

// ---------------- safety-net fallback (ws too small; not expected) --------

__global__ __launch_bounds__(256)
void sgl_naive(const float* __restrict__ w, const float* __restrict__ x,
               const int* __restrict__ idx, const float* __restrict__ coeff,
               float* __restrict__ y)
{
    __shared__ float xs[Ud];
    const int z = blockIdx.x;
    const int g = idx[z];
    for (int u = threadIdx.x; u < Ud; u += 256) xs[u] = x[(size_t)z * Ud + u];
    __syncthreads();
    const float* Wg = w + (size_t)g * (Ud * Vd);
    const float cf = coeff[0];
    for (int v = threadIdx.x; v < Vd; v += 256) {
        float acc = 0.f;
        for (int u = 0; u < Ud; ++u) acc += xs[u] * Wg[(size_t)u * Vd + v];
        y[(size_t)z * Vd + v] = acc * cf;
    }
}

extern "C" void kernel_launch(void* const* d_in, const int* in_sizes, int n_in,
                              void* d_out, int out_size, void* d_ws, size_t ws_size,
                              hipStream_t stream) {
    const float* w     = (const float*)d_in[0];
    const float* x     = (const float*)d_in[1];
    const int*   idx   = (const int*)d_in[2];
    const float* coeff = (const float*)d_in[3];
    float* y = (float*)d_out;

    if (ws_size >= WS_NEEDED) {
        unsigned short* wsw = (unsigned short*)d_ws;
        int* starts = (int*)((char*)d_ws + (size_t)WSW_US * 2);
        hipLaunchKernelGGL(convert_w, dim3(2048), dim3(256), 0, stream,
                           w, idx, wsw, starts);
        hipLaunchKernelGGL(sgl_gemm, dim3(GRID_GEMM), dim3(256), 0, stream,
                           x, wsw, starts, coeff, y);
    } else {
        hipLaunchKernelGGL(sgl_naive, dim3(Zd), dim3(256), 0, stream,
                           w, x, idx, coeff, y);
    }
}

// Round 11
// 50.425 us; speedup vs baseline: 1.1988x; 1.1988x over previous
//
#include <hip/hip_runtime.h>
#include <stdint.h>

// Grouped linear: y[z] = coeff * x[z] @ W[idx[z]], idx sorted.
// C=8, U=V=512, Z=32768, fp32 in/out, bf16 MFMA compute.
//
// R11 = R9 with the A fp32 reg-prefetch deepened to 3 sets (2 full K-steps
// of latency cover, ~550+ cy) -- single-variable test of the "exposed x-load
// latency" theory. B: 3-buffer gload_lds ring (2-step cover). Steady-state
// outstanding VM at each barrier = 2(B)+4(A)+4(A) = 10 -> vmcnt(10) no-op;
// barrier drains lgkm only.

#define Cg 8
#define Ud 512
#define Vd 512
#define Zd 32768

#define BM 128
#define BN 128
#define BK 32
#define KT 16

#define TILE_US 4096             // 128 x 32 bf16 = 8 KiB
#define NBN 4
#define NBM_MAX 263              // sum ceil(cnt_g/128) <= 256+7
#define GRID_GEMM (NBM_MAX * NBN)    // 1052

#define WSW_US (Cg * NBN * KT * TILE_US)     // 4 MiB of bf16
#define WS_NEEDED ((size_t)WSW_US * 2 + 64)

typedef __attribute__((ext_vector_type(8))) short bf16x8;
typedef __attribute__((ext_vector_type(4))) float f32x4;
typedef __attribute__((ext_vector_type(4))) unsigned short us4;
typedef __attribute__((ext_vector_type(4))) float float4v;
typedef __attribute__((ext_vector_type(4))) unsigned int u32x4;

typedef __attribute__((address_space(3))) unsigned int lds_uint;
typedef const __attribute__((address_space(1))) unsigned int gbl_uint;

__device__ __forceinline__ unsigned short f2bf(float f) {
    unsigned int u = __float_as_uint(f);
    u += 0x7fffu + ((u >> 16) & 1u);   // round-to-nearest-even
    return (unsigned short)(u >> 16);
}
__device__ __forceinline__ unsigned int pk2(float lo, float hi) {
    return (unsigned int)f2bf(lo) | ((unsigned int)f2bf(hi) << 16);
}

// Subtile layout within one [128 r][32 k] tile (ushort offset):
//   (r>>4)*512 + (k>>3)*128 + (r&15)*8 + (k&7)
// Frag read (lane l): byte = rt*1024 + l4*256 + l15*16 -> contiguous 1 KiB
// per frag across the wave: conflict-free ds_read_b128 (R2/R6-verified).

// ---------------- w converter (+ group starts) ----------------

__global__ __launch_bounds__(256)
void convert_w(const float* __restrict__ w, const int* __restrict__ idx,
               unsigned short* __restrict__ wsw, int* __restrict__ starts)
{
    const int t = blockIdx.x * 256 + threadIdx.x;    // 524288 tasks
    const int g   = t >> 16;
    const int rem = t & 65535;
    const int u0  = (rem >> 9) << 2;                 // 4 k-rows
    const int v   = rem & 511;
    const float* src = w + ((size_t)g << 18) + (size_t)u0 * Vd + v;
    us4 p;
    p[0] = f2bf(src[0]);
    p[1] = f2bf(src[Vd]);
    p[2] = f2bf(src[2 * Vd]);
    p[3] = f2bf(src[3 * Vd]);
    const int r = v & 127, k = u0 & 31;
    const int tile = (g * NBN + (v >> 7)) * KT + (u0 >> 5);
    const int off  = tile * TILE_US
                   + ((r >> 4) << 9) + ((k >> 3) << 7) + ((r & 15) << 3) + (k & 7);
    *(us4*)(wsw + off) = p;

    if (blockIdx.x == 0 && threadIdx.x < 9) {
        const int gq = threadIdx.x;
        int lo = 0;
        if (gq >= 8) lo = Zd;
        else {
            int hi = Zd;
            while (lo < hi) { int mid = (lo + hi) >> 1;
                              if (idx[mid] < gq) lo = mid + 1; else hi = mid; }
        }
        starts[gq] = lo;
    }
}

// ---------------- GEMM ----------------

#define LDA(KTV, R) do {                                                      \
    const float* p_ = ax + (KTV) * BK;                                        \
    R[0] = *(const float4v*)(p_);                                             \
    R[1] = *(const float4v*)(p_ + 4);                                         \
    R[2] = *(const float4v*)(p_ + 8);                                         \
    R[3] = *(const float4v*)(p_ + 12); } while (0)

#define CVW(BUF, R) do {                                                      \
    u32x4 w1_, w2_;                                                           \
    w1_[0] = pk2(R[0][0], R[0][1]); w1_[1] = pk2(R[0][2], R[0][3]);           \
    w1_[2] = pk2(R[1][0], R[1][1]); w1_[3] = pk2(R[1][2], R[1][3]);           \
    w2_[0] = pk2(R[2][0], R[2][1]); w2_[1] = pk2(R[2][2], R[2][3]);           \
    w2_[2] = pk2(R[3][0], R[3][1]); w2_[3] = pk2(R[3][2], R[3][3]);           \
    *(u32x4*)(&BUF[aw])       = w1_;                                          \
    *(u32x4*)(&BUF[aw + 128]) = w2_; } while (0)

#define GLB(KTV, J) do {                                                      \
    const unsigned short* s_ = wB + (size_t)(KTV) * TILE_US;                  \
    __builtin_amdgcn_global_load_lds((gbl_uint*)(s_ + bo),                    \
                                     (lds_uint*)(&Bs[J][bo]), 16, 0, 0);      \
    __builtin_amdgcn_global_load_lds((gbl_uint*)(s_ + bo + 2048),             \
                                     (lds_uint*)(&Bs[J][bo + 2048]), 16, 0, 0); \
  } while (0)

#define CMP(ABUF, J) do {                                                     \
    bf16x8 a_[4], b_[4];                                                      \
    _Pragma("unroll")                                                         \
    for (int mi_ = 0; mi_ < 4; ++mi_)                                         \
        a_[mi_] = *(const bf16x8*)(&ABUF[((wm4 + mi_) << 9) + fr]);           \
    _Pragma("unroll")                                                         \
    for (int ni_ = 0; ni_ < 4; ++ni_)                                         \
        b_[ni_] = *(const bf16x8*)(&Bs[J][((wn4 + ni_) << 9) + fr]);          \
    _Pragma("unroll")                                                         \
    for (int mi_ = 0; mi_ < 4; ++mi_)                                         \
        _Pragma("unroll")                                                     \
        for (int ni_ = 0; ni_ < 4; ++ni_)                                     \
            acc[mi_][ni_] = __builtin_amdgcn_mfma_f32_16x16x32_bf16(          \
                a_[mi_], b_[ni_], acc[mi_][ni_], 0, 0, 0);                    \
  } while (0)

#define WAITBAR(N) do {                                                       \
    asm volatile("s_waitcnt vmcnt(" #N ") lgkmcnt(0)" ::: "memory");          \
    __builtin_amdgcn_s_barrier(); } while (0)

#define SBAR() __builtin_amdgcn_sched_barrier(0)

__global__ __launch_bounds__(256, 3)
void sgl_gemm(const float* __restrict__ x,
              const unsigned short* __restrict__ wsw,
              const int* __restrict__ starts,
              const float* __restrict__ coeff,
              float* __restrict__ y)
{
    __shared__ unsigned short As[2][TILE_US];    // 16 KiB
    __shared__ unsigned short Bs[3][TILE_US];    // 24 KiB

    const int tid = threadIdx.x, lane = tid & 63, wave = tid >> 6;
    const int l15 = lane & 15, l4 = lane >> 4;

    // bijective XCD swizzle (m204): nwg=1052, q=131, r=4; consecutive wk
    // share bmp -> the 4 bn-blocks of one x-panel land on one XCD (L2 reuse).
    const int bid = blockIdx.x;
    const int xcd = bid & 7, io = bid >> 3;
    const int wk  = (xcd < 4) ? xcd * 132 + io : 528 + (xcd - 4) * 131 + io;
    const int bmp = wk >> 2, bn = wk & 3;

    // locate group for this padded row-block
    int s[9];
#pragma unroll
    for (int i = 0; i < 9; ++i) s[i] = starts[i];
    int g = -1, lblk = 0, ab = 0;
#pragma unroll
    for (int gg = 0; gg < 8; ++gg) {
        const int c  = s[gg + 1] - s[gg];
        const int nb = (c + BM - 1) >> 7;
        if (g < 0 && bmp < ab + nb) { g = gg; lblk = bmp - ab; }
        ab += nb;
    }
    if (g < 0) return;
    const int start = s[g];
    const int cnt   = s[g + 1] - s[g];
    const int j0    = lblk << 7;

    // A: thread t -> row t>>1 (coalesced pairs), k-half (t&1)*16; clamp pads
    const int ar = tid >> 1;
    const int ak = (tid & 1) << 4;
    const int rc = (j0 + ar < cnt) ? (j0 + ar) : (cnt - 1);
    const float* ax = x + (size_t)(start + rc) * Ud + ak;
    const int aw = ((ar >> 4) << 9) + ((ak >> 3) << 7) + ((ar & 15) << 3);

    // B: linear gload_lds from pre-tiled ws (8 KiB tile, 2 x 16B per thread)
    const unsigned short* wB = wsw + (size_t)((g * NBN + bn) * KT) * TILE_US;
    const int bo = tid * 8;

    const int wm4 = (wave >> 1) << 2;
    const int wn4 = (wave & 1) << 2;
    const int fr  = (l4 << 7) + (l15 << 3);

    f32x4 acc[4][4];
#pragma unroll
    for (int mi = 0; mi < 4; ++mi)
#pragma unroll
        for (int ni = 0; ni < 4; ++ni)
            acc[mi][ni] = f32x4{0.f, 0.f, 0.f, 0.f};

    float4v A0[4], A1[4], A2[4];   // 3 rotating A reg-sets (2-step cover)

    // prologue: B0,B1 + A0,A1,A2 in flight; cvt A(0); barrier.
    // Issue: GLB(0)[2], LDA(0)[4], GLB(1)[2], LDA(1)[4], LDA(2)[4] = 16.
    // CVW(A0) auto-waits A(0) -> drains GLB(0) too; leaves 10 outstanding.
    GLB(0, 0);
    SBAR();
    LDA(0, A0);
    SBAR();
    GLB(1, 1);
    SBAR();
    LDA(1, A1);
    SBAR();
    LDA(2, A2);
    SBAR();
    CVW(As[0], A0);
    WAITBAR(10);                   // vmcnt no-op; lgkm drain; B0/As0 ready

    // steady kt=0..12: GLB(kt+2), LDA(kt+3) into set kt%3, CVW tile kt+1
    // from set (kt+1)%3, CMP tile kt. Outstanding at barrier = 10.
#pragma unroll
    for (int kt = 0; kt < 13; ++kt) {
        GLB(kt + 2, (kt + 2) % 3);
        SBAR();
        switch (kt % 3) {          // LDA(kt+3) -> set (kt+3)%3 == kt%3
            case 0: LDA(kt + 3, A0); break;
            case 1: LDA(kt + 3, A1); break;
            default: LDA(kt + 3, A2); break;
        }
        SBAR();
        switch ((kt + 1) % 3) {    // CVW tile kt+1 (regs loaded at kt-2)
            case 0: CVW(As[(kt + 1) & 1], A0); break;
            case 1: CVW(As[(kt + 1) & 1], A1); break;
            default: CVW(As[(kt + 1) & 1], A2); break;
        }
        CMP(As[kt & 1], kt % 3);
        WAITBAR(10);
    }
    // kt = 13: GLB(15) only; outstanding at barrier = B(15)+A(15) = 6
    GLB(15, (15) % 3);
    SBAR();
    CVW(As[14 & 1], A2);           // tile 14 -> set 14%3 = 2
    CMP(As[13 & 1], 13 % 3);
    WAITBAR(6);
    // kt = 14: CVW tile 15 (set 15%3=0); auto-wait drains A(15); then bar 0
    CVW(As[15 & 1], A0);
    CMP(As[14 & 1], 14 % 3);
    WAITBAR(0);
    // kt = 15
    CMP(As[15 & 1], 15 % 3);

    // epilogue: C/D col=lane&15, row=(lane>>4)*4+q; mask padded rows
    const float cf = coeff[0];
    const bool full = (j0 + BM) <= cnt;
#pragma unroll
    for (int mi = 0; mi < 4; ++mi) {
        const int rb = ((wave >> 1) << 6) + mi * 16 + l4 * 4;
#pragma unroll
        for (int ni = 0; ni < 4; ++ni) {
            const int c = bn * BN + ((wave & 1) << 6) + ni * 16 + l15;
#pragma unroll
            for (int q = 0; q < 4; ++q) {
                if (full || (j0 + rb + q) < cnt)
                    y[(size_t)(start + j0 + rb + q) * Vd + c] = acc[mi][ni][q] * cf;
            }
        }
    }
}

// ---------------- safety-net fallback (ws too small; not expected) --------

__global__ __launch_bounds__(256)
void sgl_naive(const float* __restrict__ w, const float* __restrict__ x,
               const int* __restrict__ idx, const float* __restrict__ coeff,
               float* __restrict__ y)
{
    __shared__ float xs[Ud];
    const int z = blockIdx.x;
    const int g = idx[z];
    for (int u = threadIdx.x; u < Ud; u += 256) xs[u] = x[(size_t)z * Ud + u];
    __syncthreads();
    const float* Wg = w + (size_t)g * (Ud * Vd);
    const float cf = coeff[0];
    for (int v = threadIdx.x; v < Vd; v += 256) {
        float acc = 0.f;
        for (int u = 0; u < Ud; ++u) acc += xs[u] * Wg[(size_t)u * Vd + v];
        y[(size_t)z * Vd + v] = acc * cf;
    }
}

extern "C" void kernel_launch(void* const* d_in, const int* in_sizes, int n_in,
                              void* d_out, int out_size, void* d_ws, size_t ws_size,
                              hipStream_t stream) {
    const float* w     = (const float*)d_in[0];
    const float* x     = (const float*)d_in[1];
    const int*   idx   = (const int*)d_in[2];
    const float* coeff = (const float*)d_in[3];
    float* y = (float*)d_out;

    if (ws_size >= WS_NEEDED) {
        unsigned short* wsw = (unsigned short*)d_ws;
        int* starts = (int*)((char*)d_ws + (size_t)WSW_US * 2);
        hipLaunchKernelGGL(convert_w, dim3(2048), dim3(256), 0, stream,
                           w, idx, wsw, starts);
        hipLaunchKernelGGL(sgl_gemm, dim3(GRID_GEMM), dim3(256), 0, stream,
                           x, wsw, starts, coeff, y);
    } else {
        hipLaunchKernelGGL(sgl_naive, dim3(Zd), dim3(256), 0, stream,
                           w, x, idx, coeff, y);
    }
}